// Round 1
// baseline (433.940 us; speedup 1.0000x reference)
//
#include <hip/hip_runtime.h>

#define H_IMG 1080
#define W_IMG 1920
#define NPIX (H_IMG * W_IMG)

// grids: (N=50, F=16, L=8, GH=16, GW=16) -> grid_t: (L, GH, GW, F) for cam_idx
__global__ void grid_transpose_kernel(const float* __restrict__ grids,
                                      const int* __restrict__ cam_idx,
                                      float* __restrict__ grid_t) {
    int idx = blockIdx.x * blockDim.x + threadIdx.x;
    if (idx >= 8 * 16 * 16 * 16) return;
    int f = idx & 15;
    int x = (idx >> 4) & 15;
    int y = (idx >> 8) & 15;
    int z = (idx >> 12) & 7;
    int cam = cam_idx[0];
    grid_t[idx] = grids[(((cam * 16 + f) * 8 + z) * 16 + y) * 16 + x];
}

__device__ __forceinline__ float fast_tanh(float x) {
    // tanh(x) = 1 - 2/(exp(2x)+1); exact at +-inf, error ~1e-6
    float e = __expf(2.0f * x);
    return 1.0f - 2.0f * __builtin_amdgcn_rcpf(e + 1.0f);
}

__global__ __launch_bounds__(256)
void nbat_main(const float* __restrict__ rgb,
               const float* __restrict__ grid_t,
               const float* __restrict__ W1,
               const float* __restrict__ W2,
               const float* __restrict__ W3,
               float* __restrict__ out) {
    int pix = blockIdx.x * 256 + threadIdx.x;
    if (pix >= NPIX) return;
    int row = pix / W_IMG;
    int col = pix - row * W_IMG;

    float r = rgb[3 * pix + 0];
    float g = rgb[3 * pix + 1];
    float b = rgb[3 * pix + 2];
    float gray = 0.299f * r + 0.587f * g + 0.114f * b;
    gray = fminf(fmaxf(gray, 0.0f), 1.0f);

    float z = gray * 7.0f;
    float y = (float)row * (15.0f / 1079.0f);
    float x = (float)col * (15.0f / 1919.0f);
    z = fminf(fmaxf(z, 0.0f), 7.0f);
    y = fminf(fmaxf(y, 0.0f), 15.0f);
    x = fminf(fmaxf(x, 0.0f), 15.0f);

    float zf = floorf(z), yf = floorf(y), xf = floorf(x);
    int z0 = (int)zf, y0 = (int)yf, x0 = (int)xf;
    int z1 = min(z0 + 1, 7), y1 = min(y0 + 1, 15), x1 = min(x0 + 1, 15);
    float wz = z - zf, wy = y - yf, wx = x - xf;

    float feat[16];
#pragma unroll
    for (int i = 0; i < 16; ++i) feat[i] = 0.0f;

    const float4* gt4 = (const float4*)grid_t;
#pragma unroll
    for (int cz = 0; cz < 2; ++cz) {
        int zz = cz ? z1 : z0;
        float wwz = cz ? wz : (1.0f - wz);
#pragma unroll
        for (int cy = 0; cy < 2; ++cy) {
            int yy = cy ? y1 : y0;
            float wwzy = wwz * (cy ? wy : (1.0f - wy));
#pragma unroll
            for (int cx = 0; cx < 2; ++cx) {
                int xx = cx ? x1 : x0;
                float w = wwzy * (cx ? wx : (1.0f - wx));
                int base = ((zz * 16 + yy) * 16 + xx) * 4;  // float4 units
#pragma unroll
                for (int q = 0; q < 4; ++q) {
                    float4 v = gt4[base + q];
                    feat[4 * q + 0] = fmaf(w, v.x, feat[4 * q + 0]);
                    feat[4 * q + 1] = fmaf(w, v.y, feat[4 * q + 1]);
                    feat[4 * q + 2] = fmaf(w, v.z, feat[4 * q + 2]);
                    feat[4 * q + 3] = fmaf(w, v.w, feat[4 * q + 3]);
                }
            }
        }
    }

    // layer 1: h1 = tanh(feat @ W1.T), W1 is (64,16) row-major
    float h1[64];
#pragma unroll 8
    for (int j = 0; j < 64; ++j) {
        float acc = 0.0f;
#pragma unroll
        for (int k = 0; k < 16; ++k) acc = fmaf(feat[k], W1[j * 16 + k], acc);
        h1[j] = fast_tanh(acc);
    }

    // layers 2+3 fused: h2[j] folded straight into the 12 output accumulators
    float o[12];
#pragma unroll
    for (int c = 0; c < 12; ++c) o[c] = 0.0f;
#pragma unroll 4
    for (int j = 0; j < 64; ++j) {
        float acc = 0.0f;
#pragma unroll
        for (int k = 0; k < 64; ++k) acc = fmaf(h1[k], W2[j * 64 + k], acc);
        float t = fast_tanh(acc);
#pragma unroll
        for (int c = 0; c < 12; ++c) o[c] = fmaf(t, W3[c * 64 + j], o[c]);
    }

    float4* out4 = (float4*)out;
    out4[pix * 3 + 0] = make_float4(o[0], o[1], o[2], o[3]);
    out4[pix * 3 + 1] = make_float4(o[4], o[5], o[6], o[7]);
    out4[pix * 3 + 2] = make_float4(o[8], o[9], o[10], o[11]);
}

extern "C" void kernel_launch(void* const* d_in, const int* in_sizes, int n_in,
                              void* d_out, int out_size, void* d_ws, size_t ws_size,
                              hipStream_t stream) {
    const float* rgb   = (const float*)d_in[0];
    const float* grids = (const float*)d_in[1];
    const float* W1    = (const float*)d_in[2];
    const float* W2    = (const float*)d_in[3];
    const float* W3    = (const float*)d_in[4];
    const int*   cam   = (const int*)d_in[5];

    float* grid_t = (float*)d_ws;  // 32768 floats = 128 KB

    hipLaunchKernelGGL(grid_transpose_kernel, dim3(128), dim3(256), 0, stream,
                       grids, cam, grid_t);
    hipLaunchKernelGGL(nbat_main, dim3(NPIX / 256), dim3(256), 0, stream,
                       rgb, grid_t, W1, W2, W3, (float*)d_out);
}

// Round 2
// 377.863 us; speedup vs baseline: 1.1484x; 1.1484x over previous
//
#include <hip/hip_runtime.h>

#define H_IMG 1080
#define W_IMG 1920
#define NPIX (H_IMG * W_IMG)

// grids: (N=50, F=16, L=8, GH=16, GW=16) -> grid_t: (L, GH, GW, F) for cam_idx
__global__ void grid_transpose_kernel(const float* __restrict__ grids,
                                      const int* __restrict__ cam_idx,
                                      float* __restrict__ grid_t) {
    int idx = blockIdx.x * blockDim.x + threadIdx.x;
    if (idx >= 8 * 16 * 16 * 16) return;
    int f = idx & 15;
    int x = (idx >> 4) & 15;
    int y = (idx >> 8) & 15;
    int z = (idx >> 12) & 7;
    int cam = cam_idx[0];
    grid_t[idx] = grids[(((cam * 16 + f) * 8 + z) * 16 + y) * 16 + x];
}

__device__ __forceinline__ float fast_tanh(float x) {
    // tanh(x) = 1 - 2/(exp(2x)+1); exact at +-inf, error ~1e-6
    float e = __expf(2.0f * x);
    return 1.0f - 2.0f * __builtin_amdgcn_rcpf(e + 1.0f);
}

__global__ __launch_bounds__(256, 4)
void nbat_main(const float* __restrict__ rgb,
               const float* __restrict__ grid_t,
               const float* __restrict__ W1,
               const float* __restrict__ W2,
               const float* __restrict__ W3,
               float* __restrict__ out) {
    int pix = blockIdx.x * 256 + threadIdx.x;
    if (pix >= NPIX) return;
    int row = pix / W_IMG;
    int col = pix - row * W_IMG;

    float r = rgb[3 * pix + 0];
    float g = rgb[3 * pix + 1];
    float b = rgb[3 * pix + 2];
    float gray = 0.299f * r + 0.587f * g + 0.114f * b;
    gray = fminf(fmaxf(gray, 0.0f), 1.0f);

    float z = gray * 7.0f;
    float y = (float)row * (15.0f / 1079.0f);
    float x = (float)col * (15.0f / 1919.0f);
    z = fminf(fmaxf(z, 0.0f), 7.0f);
    y = fminf(fmaxf(y, 0.0f), 15.0f);
    x = fminf(fmaxf(x, 0.0f), 15.0f);

    float zf = floorf(z), yf = floorf(y), xf = floorf(x);
    int z0 = (int)zf, y0 = (int)yf, x0 = (int)xf;
    int z1 = min(z0 + 1, 7), y1 = min(y0 + 1, 15), x1 = min(x0 + 1, 15);
    float wz = z - zf, wy = y - yf, wx = x - xf;

    float feat[16];
#pragma unroll
    for (int i = 0; i < 16; ++i) feat[i] = 0.0f;

    const float4* gt4 = (const float4*)grid_t;
#pragma unroll
    for (int cz = 0; cz < 2; ++cz) {
        int zz = cz ? z1 : z0;
        float wwz = cz ? wz : (1.0f - wz);
#pragma unroll
        for (int cy = 0; cy < 2; ++cy) {
            int yy = cy ? y1 : y0;
            float wwzy = wwz * (cy ? wy : (1.0f - wy));
#pragma unroll
            for (int cx = 0; cx < 2; ++cx) {
                int xx = cx ? x1 : x0;
                float w = wwzy * (cx ? wx : (1.0f - wx));
                int base = ((zz * 16 + yy) * 16 + xx) * 4;  // float4 units
#pragma unroll
                for (int q = 0; q < 4; ++q) {
                    float4 v = gt4[base + q];
                    feat[4 * q + 0] = fmaf(w, v.x, feat[4 * q + 0]);
                    feat[4 * q + 1] = fmaf(w, v.y, feat[4 * q + 1]);
                    feat[4 * q + 2] = fmaf(w, v.z, feat[4 * q + 2]);
                    feat[4 * q + 3] = fmaf(w, v.w, feat[4 * q + 3]);
                }
            }
        }
    }

    // layer 1: h1 = tanh(feat @ W1.T), W1 is (64,16) row-major.
    // FULLY unrolled so every h1[j] index is compile-time -> stays in VGPRs
    // (previous round: partial unroll put h1 in scratch; 515 MB spill writes).
    float h1[64];
#pragma unroll
    for (int j = 0; j < 64; ++j) {
        float acc = 0.0f;
#pragma unroll
        for (int k = 0; k < 16; ++k) acc = fmaf(feat[k], W1[j * 16 + k], acc);
        h1[j] = fast_tanh(acc);
    }

    // layers 2+3 fused. Runtime j-loop (16 iters x 4 independent acc chains),
    // inner k fully unrolled -> h1[k] reads are static (register-resident).
    float o[12];
#pragma unroll
    for (int c = 0; c < 12; ++c) o[c] = 0.0f;
    for (int j = 0; j < 64; j += 4) {
        const float* w2r = W2 + j * 64;   // wave-uniform -> scalar loads
        float acc0 = 0.0f, acc1 = 0.0f, acc2 = 0.0f, acc3 = 0.0f;
#pragma unroll
        for (int k = 0; k < 64; ++k) {
            float hk = h1[k];
            acc0 = fmaf(hk, w2r[k], acc0);
            acc1 = fmaf(hk, w2r[64 + k], acc1);
            acc2 = fmaf(hk, w2r[128 + k], acc2);
            acc3 = fmaf(hk, w2r[192 + k], acc3);
        }
        float t0 = fast_tanh(acc0);
        float t1 = fast_tanh(acc1);
        float t2 = fast_tanh(acc2);
        float t3 = fast_tanh(acc3);
#pragma unroll
        for (int c = 0; c < 12; ++c) {
            float oc = o[c];
            oc = fmaf(t0, W3[c * 64 + j + 0], oc);
            oc = fmaf(t1, W3[c * 64 + j + 1], oc);
            oc = fmaf(t2, W3[c * 64 + j + 2], oc);
            oc = fmaf(t3, W3[c * 64 + j + 3], oc);
            o[c] = oc;
        }
    }

    float4* out4 = (float4*)out;
    out4[pix * 3 + 0] = make_float4(o[0], o[1], o[2], o[3]);
    out4[pix * 3 + 1] = make_float4(o[4], o[5], o[6], o[7]);
    out4[pix * 3 + 2] = make_float4(o[8], o[9], o[10], o[11]);
}

extern "C" void kernel_launch(void* const* d_in, const int* in_sizes, int n_in,
                              void* d_out, int out_size, void* d_ws, size_t ws_size,
                              hipStream_t stream) {
    const float* rgb   = (const float*)d_in[0];
    const float* grids = (const float*)d_in[1];
    const float* W1    = (const float*)d_in[2];
    const float* W2    = (const float*)d_in[3];
    const float* W3    = (const float*)d_in[4];
    const int*   cam   = (const int*)d_in[5];

    float* grid_t = (float*)d_ws;  // 32768 floats = 128 KB

    hipLaunchKernelGGL(grid_transpose_kernel, dim3(128), dim3(256), 0, stream,
                       grids, cam, grid_t);
    hipLaunchKernelGGL(nbat_main, dim3(NPIX / 256), dim3(256), 0, stream,
                       rgb, grid_t, W1, W2, W3, (float*)d_out);
}

// Round 3
// 236.497 us; speedup vs baseline: 1.8349x; 1.5977x over previous
//
#include <hip/hip_runtime.h>

#define H_IMG 1080
#define W_IMG 1920
#define NPIX (H_IMG * W_IMG)

typedef __attribute__((ext_vector_type(8))) short bfrag8;   // 8 bf16 (4 VGPRs)
typedef __attribute__((ext_vector_type(4))) float facc4;    // MFMA accumulator

// ws layout: [0,131072) grid_t f32; [131072,147456) pk2 u16; [147456,151552) pk3 u16
#define PK2_OFF 131072
#define PK3_OFF 147456

__device__ __forceinline__ void split_bf16(float x, unsigned short& hi, unsigned short& lo) {
    unsigned xu = __float_as_uint(x);
    hi = (unsigned short)(xu >> 16);                       // trunc-bf16
    float hif = __uint_as_float(xu & 0xffff0000u);
    float lof = x - hif;                                   // exact remainder
    lo = (unsigned short)(__float_as_uint(lof) >> 16);     // trunc again: |err| <= 2^-16 |x|
}

// prep: grid transpose (32768 threads) + weight fragment pre-pack (pk2/pk3)
__global__ void prep_kernel(const float* __restrict__ grids,
                            const int* __restrict__ cam_idx,
                            const float* __restrict__ W2,
                            const float* __restrict__ W3,
                            float* __restrict__ grid_t,
                            unsigned short* __restrict__ pk2,
                            unsigned short* __restrict__ pk3) {
    int idx = blockIdx.x * 256 + threadIdx.x;
    {   // grids (N,F,L,GH,GW) -> grid_t (L,GH,GW,F)
        int f = idx & 15, x = (idx >> 4) & 15, y = (idx >> 8) & 15, z = (idx >> 12) & 7;
        int cam = cam_idx[0];
        grid_t[idx] = grids[(((cam * 16 + f) * 8 + z) * 16 + y) * 16 + x];
    }
    if (idx < 8192) {  // pk2[(((nt*2+s)*2+h)*64+lane)*8+i] = half of W2T[k][j]
        int i = idx & 7, lane = (idx >> 3) & 63, h = (idx >> 9) & 1,
            s = (idx >> 10) & 1, nt = (idx >> 11) & 3;
        int j = nt * 16 + (lane & 15);
        int k = s * 32 + (lane >> 4) * 8 + i;
        unsigned short hi, lo;
        split_bf16(W2[j * 64 + k], hi, lo);
        pk2[idx] = h ? lo : hi;
    } else if (idx < 10240) {  // pk3: W3T padded to 16 cols
        int e = idx - 8192;
        int i = e & 7, lane = (e >> 3) & 63, h = (e >> 9) & 1, s = (e >> 10) & 1;
        int c = lane & 15;
        int k = s * 32 + (lane >> 4) * 8 + i;
        float x = (c < 12) ? W3[c * 64 + k] : 0.0f;
        unsigned short hi, lo;
        split_bf16(x, hi, lo);
        pk3[e] = h ? lo : hi;
    }
}

__device__ __forceinline__ float fast_tanh(float x) {
    float e = __expf(2.0f * x);
    return 1.0f - 2.0f * __builtin_amdgcn_rcpf(e + 1.0f);
}

// pack one f32 as (lo_bf16<<16)|hi_bf16 in a u32
__device__ __forceinline__ unsigned pack2(float x) {
    unsigned xu = __float_as_uint(x);
    float hif = __uint_as_float(xu & 0xffff0000u);
    float lof = x - hif;
    return (__float_as_uint(lof) & 0xffff0000u) | (xu >> 16);
}

// build hi/lo bf16x8 fragments from 8 packed u32 (two uint4)
__device__ __forceinline__ bfrag8 frag_hi(uint4 q0, uint4 q1) {
    uint4 r;
    r.x = (q0.y << 16) | (q0.x & 0xffffu);
    r.y = (q0.w << 16) | (q0.z & 0xffffu);
    r.z = (q1.y << 16) | (q1.x & 0xffffu);
    r.w = (q1.w << 16) | (q1.z & 0xffffu);
    return __builtin_bit_cast(bfrag8, r);
}
__device__ __forceinline__ bfrag8 frag_lo(uint4 q0, uint4 q1) {
    uint4 r;
    r.x = (q0.y & 0xffff0000u) | (q0.x >> 16);
    r.y = (q0.w & 0xffff0000u) | (q0.z >> 16);
    r.z = (q1.y & 0xffff0000u) | (q1.x >> 16);
    r.w = (q1.w & 0xffff0000u) | (q1.z >> 16);
    return __builtin_bit_cast(bfrag8, r);
}

__global__ __launch_bounds__(256, 2)
void nbat_main(const float* __restrict__ rgb,
               const float* __restrict__ grid_t,
               const unsigned short* __restrict__ pk2,
               const unsigned short* __restrict__ pk3,
               const float* __restrict__ W1,
               float* __restrict__ out) {
    // wave-private LDS tile [64 pixels][64 k] of packed (lo|hi) u32, XOR-swizzled:
    // u32 idx = p*64 + (k ^ ((p&15)<<2))  (16B-chunk idx = p*16 + (c ^ (p&15)))
    __shared__ __align__(16) unsigned hbuf[4][4096];  // 64 KB

    const int tid = threadIdx.x;
    const int w = tid >> 6, l = tid & 63;
    const int g = l >> 4, cc = l & 15;
    unsigned* hb = hbuf[w];
    uint4* hb4 = (uint4*)hb;

    const int pixbase = blockIdx.x * 256 + w * 64;
    const int pix = pixbase + l;
    const int row = pix / W_IMG;
    const int col = pix - row * W_IMG;

    // ---- gray + trilinear sample coords ----
    float r = rgb[3 * pix + 0];
    float gch = rgb[3 * pix + 1];
    float b = rgb[3 * pix + 2];
    float gray = fminf(fmaxf(0.299f * r + 0.587f * gch + 0.114f * b, 0.0f), 1.0f);

    float z = fminf(fmaxf(gray * 7.0f, 0.0f), 7.0f);
    float y = (float)row * (15.0f / 1079.0f);
    float x = (float)col * (15.0f / 1919.0f);

    float zf = floorf(z), yf = floorf(y), xf = floorf(x);
    int z0 = (int)zf, y0 = (int)yf, x0 = (int)xf;
    int z1 = min(z0 + 1, 7), y1 = min(y0 + 1, 15), x1 = min(x0 + 1, 15);
    float wz = z - zf, wy = y - yf, wx = x - xf;

    float feat[16];
#pragma unroll
    for (int i = 0; i < 16; ++i) feat[i] = 0.0f;

    const float4* gt4 = (const float4*)grid_t;
#pragma unroll
    for (int cz = 0; cz < 2; ++cz) {
        int zz = cz ? z1 : z0;
        float wwz = cz ? wz : (1.0f - wz);
#pragma unroll
        for (int cy = 0; cy < 2; ++cy) {
            int yy = cy ? y1 : y0;
            float wwzy = wwz * (cy ? wy : (1.0f - wy));
#pragma unroll
            for (int cx = 0; cx < 2; ++cx) {
                int xx = cx ? x1 : x0;
                float wcorner = wwzy * (cx ? wx : (1.0f - wx));
                int base = ((zz * 16 + yy) * 16 + xx) * 4;
#pragma unroll
                for (int q = 0; q < 4; ++q) {
                    float4 v = gt4[base + q];
                    feat[4 * q + 0] = fmaf(wcorner, v.x, feat[4 * q + 0]);
                    feat[4 * q + 1] = fmaf(wcorner, v.y, feat[4 * q + 1]);
                    feat[4 * q + 2] = fmaf(wcorner, v.z, feat[4 * q + 2]);
                    feat[4 * q + 3] = fmaf(wcorner, v.w, feat[4 * q + 3]);
                }
            }
        }
    }

    // ---- layer 1 (fp32 VALU, scalar W1 loads) ----
    float h1[64];
#pragma unroll
    for (int j = 0; j < 64; ++j) {
        float acc = 0.0f;
#pragma unroll
        for (int k = 0; k < 16; ++k) acc = fmaf(feat[k], W1[j * 16 + k], acc);
        h1[j] = fast_tanh(acc);
    }

    // ---- phase B: split/pack h1, write own row (p = l) ----
#pragma unroll
    for (int ch = 0; ch < 16; ++ch) {
        uint4 q;
        q.x = pack2(h1[4 * ch + 0]);
        q.y = pack2(h1[4 * ch + 1]);
        q.z = pack2(h1[4 * ch + 2]);
        q.w = pack2(h1[4 * ch + 3]);
        hb4[l * 16 + (ch ^ cc)] = q;
    }

    // ---- layer 2 via MFMA: (64 pix x 64) @ W2T (64 x 64) ----
    const bfrag8* pk2v = (const bfrag8*)pk2;
    bfrag8 b2h[4][2], b2l[4][2];
#pragma unroll
    for (int nt = 0; nt < 4; ++nt)
#pragma unroll
        for (int s = 0; s < 2; ++s) {
            b2h[nt][s] = pk2v[(((nt * 2 + s) * 2 + 0) * 64) + l];
            b2l[nt][s] = pk2v[(((nt * 2 + s) * 2 + 1) * 64) + l];
        }

    facc4 acc[4][4];
#pragma unroll
    for (int mt = 0; mt < 4; ++mt)
#pragma unroll
        for (int nt = 0; nt < 4; ++nt) acc[mt][nt] = (facc4){0.f, 0.f, 0.f, 0.f};

#pragma unroll
    for (int mt = 0; mt < 4; ++mt) {
        int prow = mt * 16 + cc;  // A row = lane&15 within tile
#pragma unroll
        for (int s = 0; s < 2; ++s) {
            int cb = 8 * s + 2 * g;  // k-chunk base: k = 32s + 8g
            uint4 q0 = hb4[prow * 16 + ((cb + 0) ^ cc)];
            uint4 q1 = hb4[prow * 16 + ((cb + 1) ^ cc)];
            bfrag8 ah = frag_hi(q0, q1);
            bfrag8 al = frag_lo(q0, q1);
#pragma unroll
            for (int nt = 0; nt < 4; ++nt) {
                acc[mt][nt] = __builtin_amdgcn_mfma_f32_16x16x32_bf16(al, b2h[nt][s], acc[mt][nt], 0, 0, 0);
                acc[mt][nt] = __builtin_amdgcn_mfma_f32_16x16x32_bf16(ah, b2l[nt][s], acc[mt][nt], 0, 0, 0);
                acc[mt][nt] = __builtin_amdgcn_mfma_f32_16x16x32_bf16(ah, b2h[nt][s], acc[mt][nt], 0, 0, 0);
            }
        }
    }

    // ---- phase D: tanh, re-split, write t back to the same LDS tile ----
    asm volatile("s_waitcnt lgkmcnt(0)" ::: "memory");
#pragma unroll
    for (int mt = 0; mt < 4; ++mt)
#pragma unroll
        for (int nt = 0; nt < 4; ++nt)
#pragma unroll
            for (int rr = 0; rr < 4; ++rr) {
                float t = fast_tanh(acc[mt][nt][rr]);
                int p = mt * 16 + g * 4 + rr;   // C row
                int j = nt * 16 + cc;           // C col
                hb[p * 64 + (j ^ ((p & 15) << 2))] = pack2(t);
            }
    asm volatile("s_waitcnt lgkmcnt(0)" ::: "memory");

    // ---- layer 3 via MFMA: (64 pix x 64) @ W3T (64 x 16-padded) ----
    const bfrag8* pk3v = (const bfrag8*)pk3;
    bfrag8 b3h[2], b3l[2];
#pragma unroll
    for (int s = 0; s < 2; ++s) {
        b3h[s] = pk3v[((s * 2 + 0) * 64) + l];
        b3l[s] = pk3v[((s * 2 + 1) * 64) + l];
    }
    facc4 o3[4];
#pragma unroll
    for (int mt = 0; mt < 4; ++mt) o3[mt] = (facc4){0.f, 0.f, 0.f, 0.f};
#pragma unroll
    for (int mt = 0; mt < 4; ++mt) {
        int prow = mt * 16 + cc;
#pragma unroll
        for (int s = 0; s < 2; ++s) {
            int cb = 8 * s + 2 * g;
            uint4 q0 = hb4[prow * 16 + ((cb + 0) ^ cc)];
            uint4 q1 = hb4[prow * 16 + ((cb + 1) ^ cc)];
            bfrag8 ah = frag_hi(q0, q1);
            bfrag8 al = frag_lo(q0, q1);
            o3[mt] = __builtin_amdgcn_mfma_f32_16x16x32_bf16(al, b3h[s], o3[mt], 0, 0, 0);
            o3[mt] = __builtin_amdgcn_mfma_f32_16x16x32_bf16(ah, b3l[s], o3[mt], 0, 0, 0);
            o3[mt] = __builtin_amdgcn_mfma_f32_16x16x32_bf16(ah, b3h[s], o3[mt], 0, 0, 0);
        }
    }

    // ---- store: lane holds out[p][cc] for p = pixbase + mt*16 + g*4 + rr ----
    if (cc < 12) {
#pragma unroll
        for (int mt = 0; mt < 4; ++mt)
#pragma unroll
            for (int rr = 0; rr < 4; ++rr) {
                int p = pixbase + mt * 16 + g * 4 + rr;
                out[p * 12 + cc] = o3[mt][rr];
            }
    }
}

extern "C" void kernel_launch(void* const* d_in, const int* in_sizes, int n_in,
                              void* d_out, int out_size, void* d_ws, size_t ws_size,
                              hipStream_t stream) {
    const float* rgb   = (const float*)d_in[0];
    const float* grids = (const float*)d_in[1];
    const float* W1    = (const float*)d_in[2];
    const float* W2    = (const float*)d_in[3];
    const float* W3    = (const float*)d_in[4];
    const int*   cam   = (const int*)d_in[5];

    float* grid_t = (float*)d_ws;
    unsigned short* pk2 = (unsigned short*)((char*)d_ws + PK2_OFF);
    unsigned short* pk3 = (unsigned short*)((char*)d_ws + PK3_OFF);

    hipLaunchKernelGGL(prep_kernel, dim3(128), dim3(256), 0, stream,
                       grids, cam, W2, W3, grid_t, pk2, pk3);
    hipLaunchKernelGGL(nbat_main, dim3(NPIX / 256), dim3(256), 0, stream,
                       rgb, grid_t, pk2, pk3, W1, (float*)d_out);
}

// Round 4
// 163.769 us; speedup vs baseline: 2.6497x; 1.4441x over previous
//
#include <hip/hip_runtime.h>

#define H_IMG 1080
#define W_IMG 1920
#define NPIX (H_IMG * W_IMG)

typedef __attribute__((ext_vector_type(8))) short bfrag8;   // 8 bf16 (4 VGPRs)
typedef __attribute__((ext_vector_type(4))) float facc4;    // MFMA accumulator

// ws layout (bytes): [0,131072) grid_t f32; [131072,147456) pk2; [147456,151552) pk3;
// [151552,159744) pk1
#define PK2_OFF 131072
#define PK3_OFF 147456
#define PK1_OFF 151552

__device__ __forceinline__ void split_bf16(float x, unsigned short& hi, unsigned short& lo) {
    unsigned xu = __float_as_uint(x);
    hi = (unsigned short)(xu >> 16);                       // trunc-bf16
    float hif = __uint_as_float(xu & 0xffff0000u);
    float lof = x - hif;                                   // exact remainder
    lo = (unsigned short)(__float_as_uint(lof) >> 16);
}

// prep: grid transpose + weight fragment pre-pack (pk1/pk2/pk3)
__global__ void prep_kernel(const float* __restrict__ grids,
                            const int* __restrict__ cam_idx,
                            const float* __restrict__ W1,
                            const float* __restrict__ W2,
                            const float* __restrict__ W3,
                            float* __restrict__ grid_t,
                            unsigned short* __restrict__ pk1,
                            unsigned short* __restrict__ pk2,
                            unsigned short* __restrict__ pk3) {
    int idx = blockIdx.x * 256 + threadIdx.x;
    {   // grids (N,F,L,GH,GW) -> grid_t (L,GH,GW,F)
        int f = idx & 15, x = (idx >> 4) & 15, y = (idx >> 8) & 15, z = (idx >> 12) & 7;
        int cam = cam_idx[0];
        grid_t[idx] = grids[(((cam * 16 + f) * 8 + z) * 16 + y) * 16 + x];
    }
    if (idx < 8192) {  // pk2[(((nt*2+s)*2+h)*64+lane)*8+i] = half of W2T[k][j]
        int i = idx & 7, lane = (idx >> 3) & 63, h = (idx >> 9) & 1,
            s = (idx >> 10) & 1, nt = (idx >> 11) & 3;
        int j = nt * 16 + (lane & 15);
        int k = s * 32 + (lane >> 4) * 8 + i;
        unsigned short hi, lo;
        split_bf16(W2[j * 64 + k], hi, lo);
        pk2[idx] = h ? lo : hi;
    } else if (idx < 10240) {  // pk3: W3T padded to 16 cols
        int e = idx - 8192;
        int i = e & 7, lane = (e >> 3) & 63, h = (e >> 9) & 1, s = (e >> 10) & 1;
        int c = lane & 15;
        int k = s * 32 + (lane >> 4) * 8 + i;
        float x = (c < 12) ? W3[c * 64 + k] : 0.0f;
        unsigned short hi, lo;
        split_bf16(x, hi, lo);
        pk3[e] = h ? lo : hi;
    } else if (idx < 14336) {  // pk1: W1T (16x64) zero-padded to K=32
        int e = idx - 10240;
        int i = e & 7, lane = (e >> 3) & 63, h = (e >> 9) & 1, nt = (e >> 10) & 3;
        int j = nt * 16 + (lane & 15);
        int k = (lane >> 4) * 8 + i;
        float x = (k < 16) ? W1[j * 16 + k] : 0.0f;
        unsigned short hi, lo;
        split_bf16(x, hi, lo);
        pk1[e] = h ? lo : hi;
    }
}

__device__ __forceinline__ float fast_tanh(float x) {
    float e = __expf(2.0f * x);
    return 1.0f - 2.0f * __builtin_amdgcn_rcpf(e + 1.0f);
}

// pack f32 -> (lo_bf16<<16)|hi_bf16 : 3 VALU ops via v_perm_b32
__device__ __forceinline__ unsigned pack2(float x) {
    unsigned xu = __float_as_uint(x);
    float lof = x - __uint_as_float(xu & 0xffff0000u);
    return __builtin_amdgcn_perm(__float_as_uint(lof), xu, 0x07060302u);
}

// hi/lo bf16x8 fragments from 8 packed u32 — one v_perm per output word
__device__ __forceinline__ bfrag8 frag_hi(uint4 q0, uint4 q1) {
    uint4 r;
    r.x = __builtin_amdgcn_perm(q0.y, q0.x, 0x05040100u);
    r.y = __builtin_amdgcn_perm(q0.w, q0.z, 0x05040100u);
    r.z = __builtin_amdgcn_perm(q1.y, q1.x, 0x05040100u);
    r.w = __builtin_amdgcn_perm(q1.w, q1.z, 0x05040100u);
    return __builtin_bit_cast(bfrag8, r);
}
__device__ __forceinline__ bfrag8 frag_lo(uint4 q0, uint4 q1) {
    uint4 r;
    r.x = __builtin_amdgcn_perm(q0.y, q0.x, 0x07060302u);
    r.y = __builtin_amdgcn_perm(q0.w, q0.z, 0x07060302u);
    r.z = __builtin_amdgcn_perm(q1.y, q1.x, 0x07060302u);
    r.w = __builtin_amdgcn_perm(q1.w, q1.z, 0x07060302u);
    return __builtin_bit_cast(bfrag8, r);
}

#define DS_FENCE() asm volatile("s_waitcnt lgkmcnt(0)" ::: "memory")

__global__ __launch_bounds__(256, 3)
void nbat_main(const float* __restrict__ rgb,
               const float* __restrict__ grid_t,
               const unsigned short* __restrict__ pk1,
               const unsigned short* __restrict__ pk2,
               const unsigned short* __restrict__ pk3,
               float* __restrict__ out) {
    // 8 KB per wave, reused 3 ways (wave-private, DS in-order):
    //  featTile [64][16] u32 (chunk swz ^ (row&3))
    //  hTile/tTile [64][32] u32 K-half (chunk swz ^ (row&7))
    __shared__ __align__(16) unsigned hbuf[4][2048];  // 32 KB/block

    const int tid = threadIdx.x;
    const int w = tid >> 6, l = tid & 63;
    const int g = l >> 4, cc = l & 15;
    unsigned* hb = hbuf[w];
    uint4* hb4 = (uint4*)hb;

    const int pixbase = blockIdx.x * 256 + w * 64;
    const int pix = pixbase + l;
    const int row = pix / W_IMG;
    const int col = pix - row * W_IMG;

    // ---- B-fragments for layer 1 (issue early, L2-resident) ----
    const bfrag8* pk1v = (const bfrag8*)pk1;
    bfrag8 b1h[4], b1l[4];
#pragma unroll
    for (int nt = 0; nt < 4; ++nt) {
        b1h[nt] = pk1v[(nt * 2 + 0) * 64 + l];
        b1l[nt] = pk1v[(nt * 2 + 1) * 64 + l];
    }

    // ---- gray + trilinear ----
    float r = rgb[3 * pix + 0];
    float gch = rgb[3 * pix + 1];
    float b = rgb[3 * pix + 2];
    float gray = fminf(fmaxf(0.299f * r + 0.587f * gch + 0.114f * b, 0.0f), 1.0f);

    float z = fminf(fmaxf(gray * 7.0f, 0.0f), 7.0f);
    float y = (float)row * (15.0f / 1079.0f);
    float x = (float)col * (15.0f / 1919.0f);

    float zf = floorf(z), yf = floorf(y), xf = floorf(x);
    int z0 = (int)zf, y0 = (int)yf, x0 = (int)xf;
    int z1 = min(z0 + 1, 7), y1 = min(y0 + 1, 15), x1 = min(x0 + 1, 15);
    float wz = z - zf, wy = y - yf, wx = x - xf;

    float feat[16];
#pragma unroll
    for (int i = 0; i < 16; ++i) feat[i] = 0.0f;

    const float4* gt4 = (const float4*)grid_t;
#pragma unroll
    for (int cz = 0; cz < 2; ++cz) {
        int zz = cz ? z1 : z0;
        float wwz = cz ? wz : (1.0f - wz);
#pragma unroll
        for (int cy = 0; cy < 2; ++cy) {
            int yy = cy ? y1 : y0;
            float wwzy = wwz * (cy ? wy : (1.0f - wy));
#pragma unroll
            for (int cx = 0; cx < 2; ++cx) {
                int xx = cx ? x1 : x0;
                float wc = wwzy * (cx ? wx : (1.0f - wx));
                int base = ((zz * 16 + yy) * 16 + xx) * 4;
#pragma unroll
                for (int q = 0; q < 4; ++q) {
                    float4 v = gt4[base + q];
                    feat[4 * q + 0] = fmaf(wc, v.x, feat[4 * q + 0]);
                    feat[4 * q + 1] = fmaf(wc, v.y, feat[4 * q + 1]);
                    feat[4 * q + 2] = fmaf(wc, v.z, feat[4 * q + 2]);
                    feat[4 * q + 3] = fmaf(wc, v.w, feat[4 * q + 3]);
                }
            }
        }
    }

    // ---- stage feat -> featTile [64][16] u32 ----
#pragma unroll
    for (int ch = 0; ch < 4; ++ch) {
        uint4 q;
        q.x = pack2(feat[4 * ch + 0]);
        q.y = pack2(feat[4 * ch + 1]);
        q.z = pack2(feat[4 * ch + 2]);
        q.w = pack2(feat[4 * ch + 3]);
        hb4[l * 4 + (ch ^ (l & 3))] = q;
    }
    DS_FENCE();

    // ---- layer 1 MFMA (K=16 zero-padded to 32; lanes g>=2 read finite garbage x B=0) ----
    facc4 acc1[4][4];
#pragma unroll
    for (int mt = 0; mt < 4; ++mt)
#pragma unroll
        for (int nt = 0; nt < 4; ++nt) acc1[mt][nt] = (facc4){0.f, 0.f, 0.f, 0.f};

#pragma unroll
    for (int mt = 0; mt < 4; ++mt) {
        int rr_ = mt * 16 + cc;
        uint4 q0 = hb4[rr_ * 4 + ((2 * (g & 1) + 0) ^ (rr_ & 3))];
        uint4 q1 = hb4[rr_ * 4 + ((2 * (g & 1) + 1) ^ (rr_ & 3))];
        bfrag8 ah = frag_hi(q0, q1);
        bfrag8 al = frag_lo(q0, q1);
#pragma unroll
        for (int nt = 0; nt < 4; ++nt) {
            acc1[mt][nt] = __builtin_amdgcn_mfma_f32_16x16x32_bf16(al, b1h[nt], acc1[mt][nt], 0, 0, 0);
            acc1[mt][nt] = __builtin_amdgcn_mfma_f32_16x16x32_bf16(ah, b1l[nt], acc1[mt][nt], 0, 0, 0);
            acc1[mt][nt] = __builtin_amdgcn_mfma_f32_16x16x32_bf16(ah, b1h[nt], acc1[mt][nt], 0, 0, 0);
        }
    }
    DS_FENCE();

    // ---- layer 2: K-split through 8 KB LDS half-tiles ----
    const bfrag8* pk2v = (const bfrag8*)pk2;
    facc4 acc2[4][4];
#pragma unroll
    for (int mt = 0; mt < 4; ++mt)
#pragma unroll
        for (int nt = 0; nt < 4; ++nt) acc2[mt][nt] = (facc4){0.f, 0.f, 0.f, 0.f};

#pragma unroll
    for (int s = 0; s < 2; ++s) {
        bfrag8 b2h[4], b2l[4];
#pragma unroll
        for (int nt = 0; nt < 4; ++nt) {
            b2h[nt] = pk2v[((nt * 2 + s) * 2 + 0) * 64 + l];
            b2l[nt] = pk2v[((nt * 2 + s) * 2 + 1) * 64 + l];
        }
        // tanh + pack cols j in [32s, 32s+32) -> hTile [64][32]
#pragma unroll
        for (int ntl = 0; ntl < 2; ++ntl) {
            int nt = 2 * s + ntl;
#pragma unroll
            for (int mt = 0; mt < 4; ++mt)
#pragma unroll
                for (int rr = 0; rr < 4; ++rr) {
                    float t = fast_tanh(acc1[mt][nt][rr]);
                    int rrow = mt * 16 + g * 4 + rr;
                    int colv = ntl * 16 + cc;
                    hb[rrow * 32 + ((((colv >> 2) ^ (rrow & 7)) << 2) | (colv & 3))] = pack2(t);
                }
        }
        DS_FENCE();
#pragma unroll
        for (int mt = 0; mt < 4; ++mt) {
            int rr_ = mt * 16 + cc;
            uint4 q0 = hb4[rr_ * 8 + ((2 * g + 0) ^ (rr_ & 7))];
            uint4 q1 = hb4[rr_ * 8 + ((2 * g + 1) ^ (rr_ & 7))];
            bfrag8 ah = frag_hi(q0, q1);
            bfrag8 al = frag_lo(q0, q1);
#pragma unroll
            for (int nt = 0; nt < 4; ++nt) {
                acc2[mt][nt] = __builtin_amdgcn_mfma_f32_16x16x32_bf16(al, b2h[nt], acc2[mt][nt], 0, 0, 0);
                acc2[mt][nt] = __builtin_amdgcn_mfma_f32_16x16x32_bf16(ah, b2l[nt], acc2[mt][nt], 0, 0, 0);
                acc2[mt][nt] = __builtin_amdgcn_mfma_f32_16x16x32_bf16(ah, b2h[nt], acc2[mt][nt], 0, 0, 0);
            }
        }
        DS_FENCE();
    }

    // ---- layer 3: same K-split pattern, N=16 (12 real) ----
    const bfrag8* pk3v = (const bfrag8*)pk3;
    facc4 o3[4];
#pragma unroll
    for (int mt = 0; mt < 4; ++mt) o3[mt] = (facc4){0.f, 0.f, 0.f, 0.f};

#pragma unroll
    for (int s = 0; s < 2; ++s) {
        bfrag8 b3h = pk3v[(s * 2 + 0) * 64 + l];
        bfrag8 b3l = pk3v[(s * 2 + 1) * 64 + l];
#pragma unroll
        for (int ntl = 0; ntl < 2; ++ntl) {
            int nt = 2 * s + ntl;
#pragma unroll
            for (int mt = 0; mt < 4; ++mt)
#pragma unroll
                for (int rr = 0; rr < 4; ++rr) {
                    float t = fast_tanh(acc2[mt][nt][rr]);
                    int rrow = mt * 16 + g * 4 + rr;
                    int colv = ntl * 16 + cc;
                    hb[rrow * 32 + ((((colv >> 2) ^ (rrow & 7)) << 2) | (colv & 3))] = pack2(t);
                }
        }
        DS_FENCE();
#pragma unroll
        for (int mt = 0; mt < 4; ++mt) {
            int rr_ = mt * 16 + cc;
            uint4 q0 = hb4[rr_ * 8 + ((2 * g + 0) ^ (rr_ & 7))];
            uint4 q1 = hb4[rr_ * 8 + ((2 * g + 1) ^ (rr_ & 7))];
            bfrag8 ah = frag_hi(q0, q1);
            bfrag8 al = frag_lo(q0, q1);
            o3[mt] = __builtin_amdgcn_mfma_f32_16x16x32_bf16(al, b3h, o3[mt], 0, 0, 0);
            o3[mt] = __builtin_amdgcn_mfma_f32_16x16x32_bf16(ah, b3l, o3[mt], 0, 0, 0);
            o3[mt] = __builtin_amdgcn_mfma_f32_16x16x32_bf16(ah, b3h, o3[mt], 0, 0, 0);
        }
        DS_FENCE();
    }

    // ---- store ----
    if (cc < 12) {
#pragma unroll
        for (int mt = 0; mt < 4; ++mt)
#pragma unroll
            for (int rr = 0; rr < 4; ++rr) {
                int p = pixbase + mt * 16 + g * 4 + rr;
                out[p * 12 + cc] = o3[mt][rr];
            }
    }
}

extern "C" void kernel_launch(void* const* d_in, const int* in_sizes, int n_in,
                              void* d_out, int out_size, void* d_ws, size_t ws_size,
                              hipStream_t stream) {
    const float* rgb   = (const float*)d_in[0];
    const float* grids = (const float*)d_in[1];
    const float* W1    = (const float*)d_in[2];
    const float* W2    = (const float*)d_in[3];
    const float* W3    = (const float*)d_in[4];
    const int*   cam   = (const int*)d_in[5];

    float* grid_t = (float*)d_ws;
    unsigned short* pk2 = (unsigned short*)((char*)d_ws + PK2_OFF);
    unsigned short* pk3 = (unsigned short*)((char*)d_ws + PK3_OFF);
    unsigned short* pk1 = (unsigned short*)((char*)d_ws + PK1_OFF);

    hipLaunchKernelGGL(prep_kernel, dim3(128), dim3(256), 0, stream,
                       grids, cam, W1, W2, W3, grid_t, pk1, pk2, pk3);
    hipLaunchKernelGGL(nbat_main, dim3(NPIX / 256), dim3(256), 0, stream,
                       rgb, grid_t, pk1, pk2, pk3, (float*)d_out);
}

// Round 5
// 150.530 us; speedup vs baseline: 2.8828x; 1.0880x over previous
//
#include <hip/hip_runtime.h>

#define H_IMG 1080
#define W_IMG 1920
#define NPIX (H_IMG * W_IMG)

typedef __attribute__((ext_vector_type(8))) short bfrag8;   // 8 bf16 (4 VGPRs)
typedef __attribute__((ext_vector_type(4))) float facc4;    // MFMA accumulator

// ws layout (bytes): [0,131072) grid_t f32; [131072,147456) pk2; [147456,151552) pk3;
// [151552,159744) pk1
#define PK2_OFF 131072
#define PK3_OFF 147456
#define PK1_OFF 151552

__device__ __forceinline__ void split_bf16(float x, unsigned short& hi, unsigned short& lo) {
    unsigned xu = __float_as_uint(x);
    hi = (unsigned short)(xu >> 16);                       // trunc-bf16
    float hif = __uint_as_float(xu & 0xffff0000u);
    float lof = x - hif;                                   // exact remainder
    lo = (unsigned short)(__float_as_uint(lof) >> 16);
}

// prep: grid transpose + weight fragment pre-pack (pk1/pk2/pk3).
// Fragment indexing (row=lane&15, k=8*(lane>>4)+i) serves as the MFMA *A* operand now.
__global__ void prep_kernel(const float* __restrict__ grids,
                            const int* __restrict__ cam_idx,
                            const float* __restrict__ W1,
                            const float* __restrict__ W2,
                            const float* __restrict__ W3,
                            float* __restrict__ grid_t,
                            unsigned short* __restrict__ pk1,
                            unsigned short* __restrict__ pk2,
                            unsigned short* __restrict__ pk3) {
    int idx = blockIdx.x * 256 + threadIdx.x;
    {   // grids (N,F,L,GH,GW) -> grid_t (L,GH,GW,F)
        int f = idx & 15, x = (idx >> 4) & 15, y = (idx >> 8) & 15, z = (idx >> 12) & 7;
        int cam = cam_idx[0];
        grid_t[idx] = grids[(((cam * 16 + f) * 8 + z) * 16 + y) * 16 + x];
    }
    if (idx < 8192) {  // pk2[(((mt*2+s)*2+h)*64+lane)*8+i] = half of W2[j=mt*16+(lane&15)][k=32s+8g+i]
        int i = idx & 7, lane = (idx >> 3) & 63, h = (idx >> 9) & 1,
            s = (idx >> 10) & 1, mt = (idx >> 11) & 3;
        int j = mt * 16 + (lane & 15);
        int k = s * 32 + (lane >> 4) * 8 + i;
        unsigned short hi, lo;
        split_bf16(W2[j * 64 + k], hi, lo);
        pk2[idx] = h ? lo : hi;
    } else if (idx < 10240) {  // pk3: W3 (12x64) zero-padded to 16 rows
        int e = idx - 8192;
        int i = e & 7, lane = (e >> 3) & 63, h = (e >> 9) & 1, s = (e >> 10) & 1;
        int c = lane & 15;
        int k = s * 32 + (lane >> 4) * 8 + i;
        float x = (c < 12) ? W3[c * 64 + k] : 0.0f;
        unsigned short hi, lo;
        split_bf16(x, hi, lo);
        pk3[e] = h ? lo : hi;
    } else if (idx < 14336) {  // pk1: W1 (64x16) zero-padded to K=32
        int e = idx - 10240;
        int i = e & 7, lane = (e >> 3) & 63, h = (e >> 9) & 1, mt = (e >> 10) & 3;
        int j = mt * 16 + (lane & 15);
        int k = (lane >> 4) * 8 + i;
        float x = (k < 16) ? W1[j * 16 + k] : 0.0f;
        unsigned short hi, lo;
        split_bf16(x, hi, lo);
        pk1[e] = h ? lo : hi;
    }
}

__device__ __forceinline__ float fast_tanh(float x) {
    float e = __expf(2.0f * x);
    return 1.0f - 2.0f * __builtin_amdgcn_rcpf(e + 1.0f);
}

// (bf16_trunc(o)<<16) | bf16_trunc(e)  — one v_perm
__device__ __forceinline__ unsigned pack_hi_pair(float e, float o) {
    return __builtin_amdgcn_perm(__float_as_uint(o), __float_as_uint(e), 0x07060302u);
}

#define DS_FENCE() asm volatile("s_waitcnt lgkmcnt(0)" ::: "memory")
#define MFMA16(A, B, C) __builtin_amdgcn_mfma_f32_16x16x32_bf16((A), (B), (C), 0, 0, 0)

__global__ __launch_bounds__(256, 3)
void nbat_main(const float* __restrict__ rgb,
               const float* __restrict__ grid_t,
               const unsigned short* __restrict__ pk1,
               const unsigned short* __restrict__ pk2,
               const unsigned short* __restrict__ pk3,
               float* __restrict__ out) {
    // per-wave 8 KB: hiTile [64 p][16 u32] at [0,1024), loTile at [1024,2048)
    // u32 addr in row: chunk c(=k/8, 0..3) swizzled c ^= (p>>1)&3
    __shared__ __align__(16) unsigned hbuf[4][2048];  // 32 KB/block

    const int tid = threadIdx.x;
    const int w = tid >> 6, l = tid & 63;
    const int g = l >> 4, cc = l & 15;
    unsigned* hb = hbuf[w];
    uint4* hb4 = (uint4*)hb;

    const int pixbase = blockIdx.x * 256 + w * 64;
    const int pix = pixbase + l;
    const int row = pix / W_IMG;
    const int col = pix - row * W_IMG;

    // ---- gray + trilinear ----
    float r = rgb[3 * pix + 0];
    float gch = rgb[3 * pix + 1];
    float b = rgb[3 * pix + 2];
    float gray = fminf(fmaxf(0.299f * r + 0.587f * gch + 0.114f * b, 0.0f), 1.0f);

    float z = fminf(fmaxf(gray * 7.0f, 0.0f), 7.0f);
    float y = (float)row * (15.0f / 1079.0f);
    float x = (float)col * (15.0f / 1919.0f);

    float zf = floorf(z), yf = floorf(y), xf = floorf(x);
    int z0 = (int)zf, y0 = (int)yf, x0 = (int)xf;
    int z1 = min(z0 + 1, 7), y1 = min(y0 + 1, 15), x1 = min(x0 + 1, 15);
    float wz = z - zf, wy = y - yf, wx = x - xf;

    float feat[16];
#pragma unroll
    for (int i = 0; i < 16; ++i) feat[i] = 0.0f;

    const float4* gt4 = (const float4*)grid_t;
#pragma unroll
    for (int cz = 0; cz < 2; ++cz) {
        int zz = cz ? z1 : z0;
        float wwz = cz ? wz : (1.0f - wz);
#pragma unroll
        for (int cy = 0; cy < 2; ++cy) {
            int yy = cy ? y1 : y0;
            float wwzy = wwz * (cy ? wy : (1.0f - wy));
#pragma unroll
            for (int cx = 0; cx < 2; ++cx) {
                int xx = cx ? x1 : x0;
                float wc = wwzy * (cx ? wx : (1.0f - wx));
                int base = ((zz * 16 + yy) * 16 + xx) * 4;
#pragma unroll
                for (int q = 0; q < 4; ++q) {
                    float4 v = gt4[base + q];
                    feat[4 * q + 0] = fmaf(wc, v.x, feat[4 * q + 0]);
                    feat[4 * q + 1] = fmaf(wc, v.y, feat[4 * q + 1]);
                    feat[4 * q + 2] = fmaf(wc, v.z, feat[4 * q + 2]);
                    feat[4 * q + 3] = fmaf(wc, v.w, feat[4 * q + 3]);
                }
            }
        }
    }

    // ---- stage featT tile: row p=l holds feat[k] bf16, k 0..15, chunks 2,3 zero ----
    const int sl = (l >> 1) & 3;
    {
        uint4 q0, q1;
        q0.x = pack_hi_pair(feat[0], feat[1]);
        q0.y = pack_hi_pair(feat[2], feat[3]);
        q0.z = pack_hi_pair(feat[4], feat[5]);
        q0.w = pack_hi_pair(feat[6], feat[7]);
        q1.x = pack_hi_pair(feat[8], feat[9]);
        q1.y = pack_hi_pair(feat[10], feat[11]);
        q1.z = pack_hi_pair(feat[12], feat[13]);
        q1.w = pack_hi_pair(feat[14], feat[15]);
        uint4 zz4 = make_uint4(0u, 0u, 0u, 0u);
        hb4[l * 4 + (0 ^ sl)] = q0;
        hb4[l * 4 + (1 ^ sl)] = q1;
        hb4[l * 4 + (2 ^ sl)] = zz4;
        hb4[l * 4 + (3 ^ sl)] = zz4;
    }
    DS_FENCE();

    // transition: tanh 4 acc values (features 16*mt+4g+rr, pixel cc+16nt),
    // exact hi/lo split, one b64 write per tile
    auto transition = [&](const facc4& v, int mtl, int nt) __attribute__((always_inline)) {
        float t0 = fast_tanh(v[0]);
        float t1 = fast_tanh(v[1]);
        float t2 = fast_tanh(v[2]);
        float t3 = fast_tanh(v[3]);
        unsigned hA = pack_hi_pair(t0, t1);
        unsigned hB = pack_hi_pair(t2, t3);
        float l0 = t0 - __uint_as_float(hA << 16);
        float l1 = t1 - __uint_as_float(hA & 0xffff0000u);
        float l2 = t2 - __uint_as_float(hB << 16);
        float l3 = t3 - __uint_as_float(hB & 0xffff0000u);
        unsigned lA = pack_hi_pair(l0, l1);
        unsigned lB = pack_hi_pair(l2, l3);
        int p = cc + 16 * nt;
        int u = p * 16 + ((((mtl << 1) + (g >> 1)) ^ ((p >> 1) & 3)) << 2) + ((g & 1) << 1);
        *(uint2*)(hb + u) = make_uint2(hA, hB);
        *(uint2*)(hb + 1024 + u) = make_uint2(lA, lB);
    };

    // ---- layer 1: C1 = W1 (64x32pad) x featT (32 x 64pix); acts 1-level ----
    const bfrag8* pk1v = (const bfrag8*)pk1;
    facc4 acc1[4][4];
#pragma unroll
    for (int mt = 0; mt < 4; ++mt)
#pragma unroll
        for (int nt = 0; nt < 4; ++nt) acc1[mt][nt] = (facc4){0.f, 0.f, 0.f, 0.f};
    {
        bfrag8 w1h[4], w1l[4];
#pragma unroll
        for (int mt = 0; mt < 4; ++mt) {
            w1h[mt] = pk1v[(mt * 2 + 0) * 64 + l];
            w1l[mt] = pk1v[(mt * 2 + 1) * 64 + l];
        }
#pragma unroll
        for (int nt = 0; nt < 4; ++nt) {
            int p = cc + 16 * nt;
            uint4 bq = hb4[p * 4 + (g ^ ((p >> 1) & 3))];
            bfrag8 bf = __builtin_bit_cast(bfrag8, bq);
#pragma unroll
            for (int mt = 0; mt < 4; ++mt) {
                acc1[mt][nt] = MFMA16(w1l[mt], bf, acc1[mt][nt]);
                acc1[mt][nt] = MFMA16(w1h[mt], bf, acc1[mt][nt]);
            }
        }
    }
    DS_FENCE();

    // ---- layer 2: C2 = W2 (64x64) x h1T, K-split s=0,1 through the 8 KB tiles ----
    const bfrag8* pk2v = (const bfrag8*)pk2;
    facc4 acc2[4][4];
#pragma unroll
    for (int mt = 0; mt < 4; ++mt)
#pragma unroll
        for (int nt = 0; nt < 4; ++nt) acc2[mt][nt] = (facc4){0.f, 0.f, 0.f, 0.f};

#pragma unroll
    for (int s = 0; s < 2; ++s) {
#pragma unroll
        for (int mtl = 0; mtl < 2; ++mtl)
#pragma unroll
            for (int nt = 0; nt < 4; ++nt) transition(acc1[2 * s + mtl][nt], mtl, nt);
        DS_FENCE();
        bfrag8 w2h[4], w2l[4];
#pragma unroll
        for (int mt = 0; mt < 4; ++mt) {
            w2h[mt] = pk2v[((mt * 2 + s) * 2 + 0) * 64 + l];
            w2l[mt] = pk2v[((mt * 2 + s) * 2 + 1) * 64 + l];
        }
#pragma unroll
        for (int nt = 0; nt < 4; ++nt) {
            int p = cc + 16 * nt;
            int sw = (p >> 1) & 3;
            uint4 qh = hb4[p * 4 + (g ^ sw)];
            uint4 ql = hb4[256 + p * 4 + (g ^ sw)];
            bfrag8 bh = __builtin_bit_cast(bfrag8, qh);
            bfrag8 bl = __builtin_bit_cast(bfrag8, ql);
#pragma unroll
            for (int mt = 0; mt < 4; ++mt) {
                acc2[mt][nt] = MFMA16(w2h[mt], bl, acc2[mt][nt]);
                acc2[mt][nt] = MFMA16(w2l[mt], bh, acc2[mt][nt]);
                acc2[mt][nt] = MFMA16(w2h[mt], bh, acc2[mt][nt]);
            }
        }
        DS_FENCE();
    }

    // ---- layer 3: O = W3 (16pad x 64) x h2T ----
    const bfrag8* pk3v = (const bfrag8*)pk3;
    facc4 o3[4];
#pragma unroll
    for (int nt = 0; nt < 4; ++nt) o3[nt] = (facc4){0.f, 0.f, 0.f, 0.f};

#pragma unroll
    for (int s = 0; s < 2; ++s) {
#pragma unroll
        for (int mtl = 0; mtl < 2; ++mtl)
#pragma unroll
            for (int nt = 0; nt < 4; ++nt) transition(acc2[2 * s + mtl][nt], mtl, nt);
        DS_FENCE();
        bfrag8 w3h = pk3v[(s * 2 + 0) * 64 + l];
        bfrag8 w3l = pk3v[(s * 2 + 1) * 64 + l];
#pragma unroll
        for (int nt = 0; nt < 4; ++nt) {
            int p = cc + 16 * nt;
            int sw = (p >> 1) & 3;
            uint4 qh = hb4[p * 4 + (g ^ sw)];
            uint4 ql = hb4[256 + p * 4 + (g ^ sw)];
            bfrag8 bh = __builtin_bit_cast(bfrag8, qh);
            bfrag8 bl = __builtin_bit_cast(bfrag8, ql);
            o3[nt] = MFMA16(w3h, bl, o3[nt]);
            o3[nt] = MFMA16(w3l, bh, o3[nt]);
            o3[nt] = MFMA16(w3h, bh, o3[nt]);
        }
        if (s == 0) DS_FENCE();
    }

    // ---- store: lane holds out features 4g..4g+3 for pixels cc+16nt; g==3 is padding ----
    if (g < 3) {
#pragma unroll
        for (int nt = 0; nt < 4; ++nt) {
            int p = pixbase + 16 * nt + cc;
            *(float4*)(out + p * 12 + 4 * g) =
                make_float4(o3[nt][0], o3[nt][1], o3[nt][2], o3[nt][3]);
        }
    }
}

extern "C" void kernel_launch(void* const* d_in, const int* in_sizes, int n_in,
                              void* d_out, int out_size, void* d_ws, size_t ws_size,
                              hipStream_t stream) {
    const float* rgb   = (const float*)d_in[0];
    const float* grids = (const float*)d_in[1];
    const float* W1    = (const float*)d_in[2];
    const float* W2    = (const float*)d_in[3];
    const float* W3    = (const float*)d_in[4];
    const int*   cam   = (const int*)d_in[5];

    float* grid_t = (float*)d_ws;
    unsigned short* pk2 = (unsigned short*)((char*)d_ws + PK2_OFF);
    unsigned short* pk3 = (unsigned short*)((char*)d_ws + PK3_OFF);
    unsigned short* pk1 = (unsigned short*)((char*)d_ws + PK1_OFF);

    hipLaunchKernelGGL(prep_kernel, dim3(128), dim3(256), 0, stream,
                       grids, cam, W1, W2, W3, grid_t, pk1, pk2, pk3);
    hipLaunchKernelGGL(nbat_main, dim3(NPIX / 256), dim3(256), 0, stream,
                       rgb, grid_t, pk1, pk2, pk3, (float*)d_out);
}